// Round 6
// baseline (4711.233 us; speedup 1.0000x reference)
//
#include <hip/hip_runtime.h>
#include <hip/hip_bf16.h>
#include <math.h>

// Fused LM-head cross-entropy: loss = mean_valid( logsumexp(x@W^T) - logit[y] )
// N=4096 tokens, H=4096 hidden, V=128000 vocab.
//
// Round 6: same m201-style 8-phase schedule as R5; single change: MFMA
// cluster issue order is now ks-OUTERMOST so consecutive MFMAs are
// independent (dependency distance 8 instead of 1). In-order issue was
// stalling on back-to-back acc chains.

#define N_ROWS 4096
#define H_DIM  4096
#define V_DIM  128000
#define BM 256
#define BN 256
#define BK 64
#define NT_N (N_ROWS / BM)     // 16
#define NT_V (V_DIM / BN)      // 500
#define NK   (H_DIM / BK)      // 64
#define IGNORE_INDEX (-100)

typedef __attribute__((ext_vector_type(8))) short bf16x8;
typedef __attribute__((ext_vector_type(4))) float f32x4;
typedef const __attribute__((address_space(1))) unsigned int* gas1_u32;
typedef __attribute__((address_space(3))) unsigned int* las3_u32;

__device__ __forceinline__ unsigned short f2bf(float f) {
    union { float f; unsigned int u; } v; v.f = f;
    return (unsigned short)((v.u + 0x8000u) >> 16);  // round-half-up to bf16
}

// ---------------- fp32 -> bf16 conversion (memory-bound) ----------------
__global__ void cvt_f32_bf16_kernel(const float* __restrict__ in,
                                    ushort* __restrict__ out, size_t n)
{
    size_t i = ((size_t)blockIdx.x * blockDim.x + threadIdx.x) * 8;
    size_t stride = (size_t)gridDim.x * blockDim.x * 8;
    for (; i < n; i += stride) {
        f32x4 a = *(const f32x4*)(in + i);
        f32x4 b = *(const f32x4*)(in + i + 4);
        ushort4 o0 = { f2bf(a.x), f2bf(a.y), f2bf(a.z), f2bf(a.w) };
        ushort4 o1 = { f2bf(b.x), f2bf(b.y), f2bf(b.z), f2bf(b.w) };
        *(ushort4*)(out + i) = o0;
        *(ushort4*)(out + i + 4) = o1;
    }
}

#define BAR()    asm volatile("s_barrier" ::: "memory")
#define LGKM0()  asm volatile("s_waitcnt lgkmcnt(0)" ::: "memory")
#define WAITV6() asm volatile("s_waitcnt vmcnt(6)" ::: "memory")
#define SETP1()  __builtin_amdgcn_s_setprio(1)
#define SETP0()  __builtin_amdgcn_s_setprio(0)

// stage one half-tile (2 x 16B gload_lds per thread); dest linear, src pre-swizzled
#define STAGE_A(BUF, HALF, KT)                                                        \
    { _Pragma("unroll")                                                               \
      for (int j_ = 0; j_ < 2; ++j_)                                                  \
          __builtin_amdgcn_global_load_lds(                                           \
              (gas1_u32)(gAr + (size_t)((HALF)*128 + j_*64) * 8192 + (size_t)(KT)*128),\
              (las3_u32)((char*)lsA + (BUF)*32768 + (HALF)*16384 + j_*8192 + tid*16), \
              16, 0, 0); }
#define STAGE_B(BUF, HALF, KT)                                                        \
    { _Pragma("unroll")                                                               \
      for (int j_ = 0; j_ < 2; ++j_)                                                  \
          __builtin_amdgcn_global_load_lds(                                           \
              (gas1_u32)(gBr + (size_t)((HALF)*128 + j_*64) * 8192 + (size_t)(KT)*128),\
              (las3_u32)((char*)lsB + (BUF)*32768 + (HALF)*16384 + j_*8192 + tid*16), \
              16, 0, 0); }

#define RD_ALO(BUF)                                                                   \
    { _Pragma("unroll")                                                               \
      for (int mi_ = 0; mi_ < 4; ++mi_) { _Pragma("unroll")                           \
        for (int ks_ = 0; ks_ < 2; ++ks_)                                             \
          aLo[mi_][ks_] = *(const bf16x8*)((const char*)lsA + (BUF)*32768 + offA[mi_][ks_]); } }
#define RD_AHI(BUF)                                                                   \
    { _Pragma("unroll")                                                               \
      for (int mi_ = 0; mi_ < 4; ++mi_) { _Pragma("unroll")                           \
        for (int ks_ = 0; ks_ < 2; ++ks_)                                             \
          aHi[mi_][ks_] = *(const bf16x8*)((const char*)lsA + (BUF)*32768 + offA[mi_ + 4][ks_]); } }
#define RD_BLO(BUF)                                                                   \
    { _Pragma("unroll")                                                               \
      for (int ni_ = 0; ni_ < 2; ++ni_) { _Pragma("unroll")                           \
        for (int ks_ = 0; ks_ < 2; ++ks_)                                             \
          bAll[ni_][ks_] = *(const bf16x8*)((const char*)lsB + (BUF)*32768 + offB[ni_][ks_]); } }
#define RD_BHI(BUF)                                                                   \
    { _Pragma("unroll")                                                               \
      for (int ni_ = 2; ni_ < 4; ++ni_) { _Pragma("unroll")                           \
        for (int ks_ = 0; ks_ < 2; ++ks_)                                             \
          bAll[ni_][ks_] = *(const bf16x8*)((const char*)lsB + (BUF)*32768 + offB[ni_][ks_]); } }

// ks OUTERMOST: 8 independent MFMAs between dependent re-accumulations.
#define MFMA_QUAD(AF, MIB, NIL)                                                       \
    { _Pragma("unroll")                                                               \
      for (int ks_ = 0; ks_ < 2; ++ks_) { _Pragma("unroll")                           \
        for (int mi_ = 0; mi_ < 4; ++mi_) { _Pragma("unroll")                         \
          for (int nn_ = 0; nn_ < 2; ++nn_)                                           \
            acc[(MIB)+mi_][(NIL)+nn_] = __builtin_amdgcn_mfma_f32_16x16x32_bf16(      \
                AF[mi_][ks_], bAll[(NIL)+nn_][ks_], acc[(MIB)+mi_][(NIL)+nn_], 0, 0, 0); } } }

// ------------------- 256^2 8-phase bf16 GEMM -------------------
__global__ __launch_bounds__(512, 2)
void lmce_gemm256_kernel(const ushort* __restrict__ Xb, const ushort* __restrict__ Wb,
                         float* __restrict__ pm, float* __restrict__ pl)
{
    // [buf][half][128 rows][64 k] bf16 = 16KB per half; 64KB per operand
    __shared__ __align__(16) ushort lsA[2][2][128 * 64];
    __shared__ __align__(16) ushort lsB[2][2][128 * 64];
    __shared__ float red_m[4][BM];
    __shared__ float red_l[4][BM];

    // bijective XCD swizzle: nwg = 8000, divisible by 8
    const int nwg = NT_N * NT_V;
    int orig = blockIdx.x;
    int wg = (orig & 7) * (nwg >> 3) + (orig >> 3);
    int vtile = wg / NT_N;
    int ntile = wg - vtile * NT_N;

    int tid  = threadIdx.x;
    int lane = tid & 63;
    int w    = tid >> 6;         // 0..7
    int wr = w >> 2;             // 0..1 : which A half this wave consumes
    int wc = w & 3;              // 0..3 : which 64-row B strip
    int fr = lane & 15;
    int kg = lane >> 4;

    // staging source: thread covers row (tid>>3) of each 64-row chunk,
    // 16B at pre-swizzled col ((tid&7) ^ ((tid>>3)&7))*16
    int scolb = ((tid & 7) ^ ((tid >> 3) & 7)) * 16;
    const char* gAr = (const char*)Xb + (size_t)(ntile * BM + (tid >> 3)) * 8192 + scolb;
    const char* gBr = (const char*)Wb + (size_t)(vtile * BN + (tid >> 3)) * 8192 + scolb;

    // swizzled ds_read offsets (within one operand buffer; add buf*32768)
    int offA[8][2];
    #pragma unroll
    for (int mi = 0; mi < 8; ++mi)
        #pragma unroll
        for (int ks = 0; ks < 2; ++ks) {
            int row = mi * 16 + fr;     // local row in half wr
            offA[mi][ks] = wr * 16384 + row * 128 + ((kg * 16 + ks * 64) ^ ((row & 7) << 4));
        }
    int offB[4][2];
    #pragma unroll
    for (int ni = 0; ni < 4; ++ni)
        #pragma unroll
        for (int ks = 0; ks < 2; ++ks) {
            int rowh = (wc & 1) * 64 + ni * 16 + fr;   // local row in half wc>>1
            offB[ni][ks] = (wc >> 1) * 16384 + rowh * 128 + ((kg * 16 + ks * 64) ^ ((rowh & 7) << 4));
        }

    f32x4 acc[8][4];
    #pragma unroll
    for (int i = 0; i < 8; ++i)
        #pragma unroll
        for (int j = 0; j < 4; ++j)
            acc[i][j] = (f32x4){0.f, 0.f, 0.f, 0.f};

    bf16x8 aLo[4][2], aHi[4][2], bAll[4][2];

    // prologue: tile0 (8 loads) + {B0(1),B1(1),A0(1)} (6 loads in flight)
    STAGE_A(0, 0, 0); STAGE_A(0, 1, 0); STAGE_B(0, 0, 0); STAGE_B(0, 1, 0);
    STAGE_B(1, 0, 1); STAGE_B(1, 1, 1); STAGE_A(1, 0, 1);
    WAITV6();
    BAR();

    for (int t = 0; t < NK; t += 2) {
        int t2 = (t + 2 < NK) ? t + 2 : NK - 1;   // clamped dummy re-stage at tail
        int t3 = (t + 3 < NK) ? t + 3 : NK - 1;

        // ---- ph0 (tile t, buf0): Q(mi0-3, ni0-1)
        RD_ALO(0); RD_BLO(0);
        STAGE_A(1, 1, t + 1);
        BAR(); LGKM0();
        SETP1(); MFMA_QUAD(aLo, 0, 0); SETP0();
        BAR();

        // ---- ph1: Q(mi0-3, ni2-3)
        RD_BHI(0);
        STAGE_B(0, 0, t2);
        BAR(); LGKM0();
        SETP1(); MFMA_QUAD(aLo, 0, 2); SETP0();
        BAR();

        // ---- ph2: Q(mi4-7, ni2-3)
        RD_AHI(0);
        STAGE_B(0, 1, t2);
        BAR(); LGKM0();
        SETP1(); MFMA_QUAD(aHi, 4, 2); SETP0();
        BAR();

        // ---- ph3: Q(mi4-7, ni0-1); tile t+1 must land before ph4 reads
        STAGE_A(0, 0, t2);
        BAR(); LGKM0();
        SETP1(); MFMA_QUAD(aHi, 4, 0); SETP0();
        WAITV6();
        BAR();

        // ---- ph4 (tile t+1, buf1): Q(mi0-3, ni0-1)
        RD_ALO(1); RD_BLO(1);
        STAGE_A(0, 1, t2);
        BAR(); LGKM0();
        SETP1(); MFMA_QUAD(aLo, 0, 0); SETP0();
        BAR();

        // ---- ph5: Q(mi0-3, ni2-3)
        RD_BHI(1);
        STAGE_B(1, 0, t3);
        BAR(); LGKM0();
        SETP1(); MFMA_QUAD(aLo, 0, 2); SETP0();
        BAR();

        // ---- ph6: Q(mi4-7, ni2-3)
        RD_AHI(1);
        STAGE_B(1, 1, t3);
        BAR(); LGKM0();
        SETP1(); MFMA_QUAD(aHi, 4, 2); SETP0();
        BAR();

        // ---- ph7: Q(mi4-7, ni0-1); tile t+2 must land before next ph0 reads
        STAGE_A(1, 0, t3);
        BAR(); LGKM0();
        SETP1(); MFMA_QUAD(aHi, 4, 0); SETP0();
        WAITV6();
        BAR();
    }

    __syncthreads();   // full drain (vmcnt 0 + lgkm 0) before epilogue

    // Epilogue: per-row max and sumexp over this block's 256 cols.
    // C/D layout (16x16x32): col = lane&15 (fr), row = kg*4 + reg.
    #pragma unroll
    for (int mi = 0; mi < 8; ++mi) {
        #pragma unroll
        for (int j = 0; j < 4; ++j) {
            float mx = fmaxf(fmaxf(acc[mi][0][j], acc[mi][1][j]),
                             fmaxf(acc[mi][2][j], acc[mi][3][j]));
            #pragma unroll
            for (int s = 1; s < 16; s <<= 1)
                mx = fmaxf(mx, __shfl_xor(mx, s, 64));
            float se = 0.f;
            #pragma unroll
            for (int ni = 0; ni < 4; ++ni)
                se += __expf(acc[mi][ni][j] - mx);
            #pragma unroll
            for (int s = 1; s < 16; s <<= 1)
                se += __shfl_xor(se, s, 64);
            if (fr == 0) {
                int rloc = wr * 128 + mi * 16 + kg * 4 + j;
                red_m[wc][rloc] = mx;
                red_l[wc][rloc] = se;
            }
        }
    }
    __syncthreads();
    if (tid < BM) {
        float mm = red_m[0][tid], ll = red_l[0][tid];
        #pragma unroll
        for (int p = 1; p < 4; ++p) {
            float m2 = red_m[p][tid], l2 = red_l[p][tid];
            float m3 = fmaxf(mm, m2);
            ll = ll * __expf(mm - m3) + l2 * __expf(m2 - m3);
            mm = m3;
        }
        size_t idx = (size_t)vtile * N_ROWS + (size_t)(ntile * BM + tid);
        pm[idx] = mm;
        pl[idx] = ll;
    }
}

// tgt[row] = dot(x[row], W[y[row]]) in fp32 (exact vs reference)
__global__ void lmce_tgt_kernel(const float* __restrict__ X, const float* __restrict__ W,
                                const int* __restrict__ y, float* __restrict__ tgt)
{
    int row = blockIdx.x;
    int tid = threadIdx.x;
    int yv = y[row];
    float s = 0.f;
    if (yv >= 0 && yv < V_DIM) {
        const float* xr = X + (size_t)row * H_DIM;
        const float* wrow = W + (size_t)yv * H_DIM;
        #pragma unroll
        for (int j = 0; j < 4; ++j) {
            int idx = (tid + j * 256) * 4;
            f32x4 a = *(const f32x4*)(xr + idx);
            f32x4 b = *(const f32x4*)(wrow + idx);
            s += a.x * b.x + a.y * b.y + a.z * b.z + a.w * b.w;
        }
    }
    #pragma unroll
    for (int sh = 1; sh < 64; sh <<= 1) s += __shfl_xor(s, sh, 64);
    __shared__ float sred[4];
    if ((tid & 63) == 0) sred[tid >> 6] = s;
    __syncthreads();
    if (tid == 0) tgt[row] = sred[0] + sred[1] + sred[2] + sred[3];
}

// merge NT_V per-vtile (m,l) partials per row -> lse[row]
__global__ void lmce_lse_kernel(const float* __restrict__ pm, const float* __restrict__ pl,
                                float* __restrict__ lse)
{
    int tid = threadIdx.x;
    int row = blockIdx.x * 64 + (tid & 63);
    int part = tid >> 6;               // 0..3, each scans NT_V/4 = 125 vtiles
    const int per = NT_V / 4;
    float m = -INFINITY, l = 0.f;
    for (int vt = part * per; vt < (part + 1) * per; ++vt) {
        size_t idx = (size_t)vt * N_ROWS + row;
        float m2 = pm[idx], l2 = pl[idx];
        float mm = fmaxf(m, m2);
        l = l * __expf(m - mm) + l2 * __expf(m2 - mm);
        m = mm;
    }
    __shared__ float sm[4][64], sl[4][64];
    sm[part][tid & 63] = m;
    sl[part][tid & 63] = l;
    __syncthreads();
    if (tid < 64) {
        float M = sm[0][tid], L = sl[0][tid];
        #pragma unroll
        for (int p = 1; p < 4; ++p) {
            float m2 = sm[p][tid], l2 = sl[p][tid];
            float mm = fmaxf(M, m2);
            L = L * __expf(M - mm) + l2 * __expf(m2 - mm);
            M = mm;
        }
        lse[blockIdx.x * 64 + tid] = M + logf(L);
    }
}

__global__ void lmce_final_kernel(const float* __restrict__ lse, const float* __restrict__ tgt,
                                  const int* __restrict__ y, float* __restrict__ out)
{
    int tid = threadIdx.x;
    float s = 0.f, c = 0.f;
    for (int i = tid; i < N_ROWS; i += 256) {
        if (y[i] != IGNORE_INDEX) {
            s += lse[i] - tgt[i];
            c += 1.f;
        }
    }
    #pragma unroll
    for (int sh = 1; sh < 64; sh <<= 1) {
        s += __shfl_xor(s, sh, 64);
        c += __shfl_xor(c, sh, 64);
    }
    __shared__ float ss[4], cc[4];
    if ((tid & 63) == 0) { ss[tid >> 6] = s; cc[tid >> 6] = c; }
    __syncthreads();
    if (tid == 0) {
        float S = ss[0] + ss[1] + ss[2] + ss[3];
        float C = cc[0] + cc[1] + cc[2] + cc[3];
        out[0] = S / fmaxf(C, 1.f);
    }
}

extern "C" void kernel_launch(void* const* d_in, const int* in_sizes, int n_in,
                              void* d_out, int out_size, void* d_ws, size_t ws_size,
                              hipStream_t stream)
{
    const float* X = (const float*)d_in[0];   // [4096, 4096] fp32
    const int*   y = (const int*)d_in[1];     // [4096] labels
    const float* W = (const float*)d_in[2];   // [128000, 4096] fp32
    float* out = (float*)d_out;

    char* ws = (char*)d_ws;
    const size_t OFF_PL  = 16384000;
    const size_t OFF_TGT = 32768000;
    const size_t OFF_LSE = 32784384;
    const size_t OFF_XB  = 32800768;
    const size_t OFF_WB  = 66355200;

    float* pm  = (float*)ws;
    float* pl  = (float*)(ws + OFF_PL);
    float* tgt = (float*)(ws + OFF_TGT);
    float* lse = (float*)(ws + OFF_LSE);
    ushort* Xb = (ushort*)(ws + OFF_XB);
    ushort* Wb = (ushort*)(ws + OFF_WB);

    cvt_f32_bf16_kernel<<<2048, 256, 0, stream>>>(W, Wb, (size_t)V_DIM * H_DIM);
    cvt_f32_bf16_kernel<<<512, 256, 0, stream>>>(X, Xb, (size_t)N_ROWS * H_DIM);
    lmce_gemm256_kernel<<<NT_N * NT_V, 512, 0, stream>>>(Xb, Wb, pm, pl);
    lmce_tgt_kernel<<<N_ROWS, 256, 0, stream>>>(X, W, y, tgt);
    lmce_lse_kernel<<<N_ROWS / 64, 256, 0, stream>>>(pm, pl, lse);
    lmce_final_kernel<<<1, 256, 0, stream>>>(lse, tgt, y, out);
}